// Round 20
// baseline (336.221 us; speedup 1.0000x reference)
//
#include <hip/hip_runtime.h>
#include <cstdint>
#include <cstddef>

#define BS_   128
#define MSL_  128
#define D_    768
#define NH_   12
#define DH_   64
#define DI_   3072
#define ROWS_ (BS_ * MSL_)   // 16384
#define MT_SZ (NH_ * MSL_ * MSL_)   // 196608 elements per M matrix

using bf16x8 = __attribute__((ext_vector_type(8))) __bf16;
using f32x4  = __attribute__((ext_vector_type(4))) float;

// Exact RNE f32 -> bf16 bits.
static __device__ __forceinline__ uint16_t f2b(float f) {
    uint32_t u = __builtin_bit_cast(uint32_t, f);
    u += 0x7fffu + ((u >> 16) & 1u);
    return (uint16_t)(u >> 16);
}
static __device__ __forceinline__ float b2f(uint16_t h) {
    uint32_t u = ((uint32_t)h) << 16;
    return __builtin_bit_cast(float, u);
}

// ---------------- batched f32 -> bf16 convert (one launch for all 9 jobs) ----
struct CvtBatch {
    const float* src[9];
    uint16_t*    dst[9];
    int          n4[9];
    int          boff[10];   // prefix block offsets
};
__global__ __launch_bounds__(256)
void cvt_batch(CvtBatch cb) {
    const int g = blockIdx.x;
    int seg = 0;
    while (seg < 8 && g >= cb.boff[seg + 1]) ++seg;
    const int i = (g - cb.boff[seg]) * 256 + threadIdx.x;
    if (i < cb.n4[seg]) {
        float4 v = ((const float4*)cb.src[seg])[i];
        ushort4 o;
        o.x = f2b(v.x); o.y = f2b(v.y); o.z = f2b(v.z); o.w = f2b(v.w);
        ((ushort4*)cb.dst[seg])[i] = o;
    }
}

// async global->LDS, 16B per lane. LDS dest is wave-uniform base (+lane*16 in HW).
static __device__ __forceinline__ void gload16(const uint16_t* g, uint16_t* l) {
    __builtin_amdgcn_global_load_lds(
        (__attribute__((address_space(1))) void*)(uintptr_t)g,
        (__attribute__((address_space(3))) void*)(uintptr_t)l,
        16, 0, 0);
}

#define BAR_()  __builtin_amdgcn_s_barrier()
#define LGKM_() asm volatile("s_waitcnt lgkmcnt(0)" ::: "memory")

// ---------------- bf16 MFMA GEMM: C = epi(A @ B^T + bias) ----------------
// A: [M][K] bf16 rows at stride lda, B: [N][K] bf16 row-major, C: [M][N] bf16.
// EPI: 0 = +bias; 1 = (+bias)*scale+shift; 2 = relu(+bias)
// BM: 256 (512 thr, 8 waves, 128KB LDS) or 128 (256 thr, 4 waves, 64KB LDS
//     -> 2 blk/CU; r11/r19: co-residency covers barrier drains, ~1190 TF).
// CP (column-pair supergroups): within each XCD chunk (ry rows x gx cols),
//   iterate 2-col x ry-row supergroups -> L2 working set = ry A-panels +
//   2 B-panels < 4MB (for K=768 shapes). Confirmed FETCH 72->57MB (r19);
//   combined with BM=128 for the 2-blk/CU schedule benefit (this round).
// 8-phase counted-vmcnt schedule (r9-proven, de-pinned; no sched_barrier).
// LDS chunk swizzle: phys16Bchunk = logical ^ (row&7), BOTH sides (rule #21).
// XCD swizzle bijective when nwg%8==0; identity fallback otherwise.
template<int EPI, int BM, int CP>
__global__ __launch_bounds__(BM * 2, 2)
void gemm_bf16(const uint16_t* __restrict__ A, const uint16_t* __restrict__ B,
               const float* __restrict__ bias, const float* __restrict__ scale,
               const float* __restrict__ shift, uint16_t* __restrict__ C,
               int M, int N, int K, int gx, int lda)
{
    constexpr int NTHR = BM * 2;
    constexpr int FR   = BM / 64;
    __shared__ __align__(16) uint16_t As[2][BM * 64];
    __shared__ __align__(16) uint16_t Bs[2][BM * 64];
    const int tid  = threadIdx.x;
    const int lane = tid & 63;
    const int m_   = lane & 15;
    const int kg   = lane >> 4;
    const int w    = tid >> 6;
    const int wr   = w / FR;
    const int wc   = w % FR;

    const int nwg = gridDim.x;
    const int q   = nwg >> 3;
    int m0, n0;
    if constexpr (CP) {
        // XCD chunk: rows [x*ry, (x+1)*ry) x all gx cols; 2-col supergroups
        // of ry rows each (generalized from r18's fixed-8).
        const int x   = blockIdx.x & 7;
        const int lid = blockIdx.x >> 3;       // [0, q)
        const int ry  = q / gx;                // rows per XCD chunk
        const int g2  = 2 * ry;
        const int sg  = lid / g2;              // supergroup (2 cols x ry rows)
        const int r   = lid % g2;
        m0 = (x * ry + (r >> 1)) * BM;
        n0 = (sg * 2 + (r & 1)) * BM;
    } else {
        const int wg = ((nwg & 7) == 0) ? ((blockIdx.x & 7) * q + (blockIdx.x >> 3))
                                        : (int)blockIdx.x;
        m0 = (wg / gx) * BM;
        n0 = (wg % gx) * BM;
    }

    f32x4 acc[2 * FR][4] = {};

    int srow[4], ssl[4], sbase[4];
#pragma unroll
    for (int it = 0; it < 4; ++it) {
        const int c = it * NTHR + tid;
        srow[it]  = c >> 3;
        ssl[it]   = (c & 7) ^ (srow[it] & 7);
        sbase[it] = (it * NTHR + (tid & (NTHR - 64))) * 8;
    }
    auto stageA = [&](int buf, int k0, int half) {
        const int it0 = half * 2, it1 = it0 + 1;
        gload16(A + (size_t)(m0 + srow[it0]) * lda + k0 + ssl[it0] * 8, &As[buf][sbase[it0]]);
        gload16(A + (size_t)(m0 + srow[it1]) * lda + k0 + ssl[it1] * 8, &As[buf][sbase[it1]]);
    };
    auto stageB = [&](int buf, int k0, int half) {
        const int it0 = half * 2, it1 = it0 + 1;
        gload16(B + (size_t)(n0 + srow[it0]) * K + k0 + ssl[it0] * 8, &Bs[buf][sbase[it0]]);
        gload16(B + (size_t)(n0 + srow[it1]) * K + k0 + ssl[it1] * 8, &Bs[buf][sbase[it1]]);
    };

    auto rdAh = [&](const uint16_t* S, int half, bf16x8 (&dst)[FR][2]) {
#pragma unroll
        for (int i = 0; i < FR; ++i) {
            const int row = wr * (BM / 2) + half * (FR * 16) + i * 16 + m_;
#pragma unroll
            for (int kk = 0; kk < 2; ++kk)
                dst[i][kk] = *reinterpret_cast<const bf16x8*>(
                    &S[row * 64 + (((kk * 4 + kg) ^ (m_ & 7)) * 8)]);
        }
    };
    auto rdBp = [&](const uint16_t* S, int jp, bf16x8 (&dst)[2][2]) {
#pragma unroll
        for (int j = 0; j < 2; ++j) {
            const int row = wc * 64 + (jp * 2 + j) * 16 + m_;
#pragma unroll
            for (int kk = 0; kk < 2; ++kk)
                dst[j][kk] = *reinterpret_cast<const bf16x8*>(
                    &S[row * 64 + (((kk * 4 + kg) ^ (m_ & 7)) * 8)]);
        }
    };
    auto mfmaQ = [&](bf16x8 (&A4)[FR][2], bf16x8 (&B2)[2][2], int io, int jo) {
        __builtin_amdgcn_s_setprio(1);
#pragma unroll
        for (int i = 0; i < FR; ++i)
#pragma unroll
            for (int j = 0; j < 2; ++j) {
                acc[io + i][jo + j] = __builtin_amdgcn_mfma_f32_16x16x32_bf16(
                    A4[i][0], B2[j][0], acc[io + i][jo + j], 0, 0, 0);
                acc[io + i][jo + j] = __builtin_amdgcn_mfma_f32_16x16x32_bf16(
                    A4[i][1], B2[j][1], acc[io + i][jo + j], 0, 0, 0);
            }
        __builtin_amdgcn_s_setprio(0);
    };

    stageA(0, 0, 0); stageA(0, 0, 1); stageB(0, 0, 0); stageB(0, 0, 1);
    stageA(1, 64, 0); stageA(1, 64, 1);
    asm volatile("s_waitcnt vmcnt(4)" ::: "memory");
    BAR_();

    bf16x8 aLo[FR][2], aHi[FR][2], bLo[2][2], bHi[2][2];
    const int NT = K >> 6;
    for (int t = 0; t < NT; t += 2) {
        const bool last = (t + 2 >= NT);
        const int k1 = (t + 1) << 6, k2 = (t + 2) << 6, k3 = (t + 3) << 6;

        rdAh(As[0], 0, aLo); rdBp(Bs[0], 0, bLo);
        stageB(1, k1, 0);
        BAR_(); LGKM_(); mfmaQ(aLo, bLo, 0, 0); BAR_();
        rdAh(As[0], 1, aHi);
        stageB(1, k1, 1);
        BAR_(); LGKM_(); mfmaQ(aHi, bLo, FR, 0); BAR_();
        rdBp(Bs[0], 1, bHi);
        if (!last) stageA(0, k2, 0);
        BAR_(); LGKM_(); mfmaQ(aLo, bHi, 0, 2); BAR_();
        if (!last) { stageA(0, k2, 1);
                     asm volatile("s_waitcnt vmcnt(4)" ::: "memory"); }
        else       { asm volatile("s_waitcnt vmcnt(0)" ::: "memory"); }
        BAR_(); mfmaQ(aHi, bHi, FR, 2); BAR_();

        rdAh(As[1], 0, aLo); rdBp(Bs[1], 0, bLo);
        if (!last) stageB(0, k2, 0);
        BAR_(); LGKM_(); mfmaQ(aLo, bLo, 0, 0); BAR_();
        rdAh(As[1], 1, aHi);
        if (!last) stageB(0, k2, 1);
        BAR_(); LGKM_(); mfmaQ(aHi, bLo, FR, 0); BAR_();
        rdBp(Bs[1], 1, bHi);
        if (!last) stageA(1, k3, 0);
        BAR_(); LGKM_(); mfmaQ(aLo, bHi, 0, 2); BAR_();
        if (!last) { stageA(1, k3, 1);
                     asm volatile("s_waitcnt vmcnt(4)" ::: "memory"); }
        BAR_(); mfmaQ(aHi, bHi, FR, 2); BAR_();
    }

    const int r0 = m0 + wr * (BM / 2);
    const int c0 = n0 + wc * 64;
#pragma unroll
    for (int i = 0; i < 2 * FR; ++i) {
#pragma unroll
        for (int j = 0; j < 4; ++j) {
            const int col = c0 + j * 16 + m_;
            const float bs = bias[col];
#pragma unroll
            for (int r = 0; r < 4; ++r) {
                float v = acc[i][j][r] + bs;
                if constexpr (EPI == 1) v = v * scale[col] + shift[col];
                if constexpr (EPI == 2) v = fmaxf(v, 0.f);
                const int rowo = r0 + i * 16 + kg * 4 + r;
                C[(size_t)rowo * N + col] = f2b(v);
            }
        }
    }
}

// ---------- Fused V-GEMM + head mixing (BM=128, one batch per M-tile) -------
// Stage 1: V-tile[s=0..127][128 hd-cols] = hin[b] @ Wv^T + b  (8-phase loop).
// Stash V (bf16) into dead As LDS using the proven chunk-XOR layout.
// Stage 2 (T0=0): out[b,t,hd] = sum_s MhT[h][t][s] * V[s][hd]  (K=128 MFMA).
// Stage 2 (T0=1, block 2): only t=0 survives — all 256 threads: each column
// handled by 2 threads (s-halves), partials combined via LDS.
template<int T0>
__global__ __launch_bounds__(256, 2)
void fused_vmix(const uint16_t* __restrict__ A, const uint16_t* __restrict__ B,
                const float* __restrict__ bias, const uint16_t* __restrict__ MhT,
                uint16_t* __restrict__ out, int gx)
{
    constexpr int BM = 128, NTHR = 256, FR = 2;
    const int K = D_;
    __shared__ __align__(16) uint16_t As[2][BM * 64];
    __shared__ __align__(16) uint16_t Bs[2][BM * 64];
    __shared__ float Pred[128];
    const int tid  = threadIdx.x;
    const int lane = tid & 63;
    const int m_   = lane & 15;
    const int kg   = lane >> 4;
    const int w    = tid >> 6;
    const int wr   = w / FR;   // 0..1 (s-half / t-half)
    const int wc   = w % FR;   // 0..1 (hd-half; also head within pair)

    const int nwg = gridDim.x;        // 768 (%8==0)
    const int q   = nwg >> 3;
    const int wg  = (blockIdx.x & 7) * q + (blockIdx.x >> 3);
    const int bb  = wg / gx;          // batch
    const int hp  = wg % gx;          // head pair
    const int m0  = bb * BM;          // rows of A (= b*128 + s)
    const int n0  = hp * BM;          // hd column base

    f32x4 acc[4][4] = {};

    int srow[4], ssl[4], sbase[4];
#pragma unroll
    for (int it = 0; it < 4; ++it) {
        const int c = it * NTHR + tid;
        srow[it]  = c >> 3;
        ssl[it]   = (c & 7) ^ (srow[it] & 7);
        sbase[it] = (it * NTHR + (tid & (NTHR - 64))) * 8;
    }
    auto stageA = [&](int buf, int k0, int half) {
        const int it0 = half * 2, it1 = it0 + 1;
        gload16(A + (size_t)(m0 + srow[it0]) * K + k0 + ssl[it0] * 8, &As[buf][sbase[it0]]);
        gload16(A + (size_t)(m0 + srow[it1]) * K + k0 + ssl[it1] * 8, &As[buf][sbase[it1]]);
    };
    auto stageB = [&](int buf, int k0, int half) {
        const int it0 = half * 2, it1 = it0 + 1;
        gload16(B + (size_t)(n0 + srow[it0]) * K + k0 + ssl[it0] * 8, &Bs[buf][sbase[it0]]);
        gload16(B + (size_t)(n0 + srow[it1]) * K + k0 + ssl[it1] * 8, &Bs[buf][sbase[it1]]);
    };
    auto rdAh = [&](const uint16_t* S, int half, bf16x8 (&dst)[FR][2]) {
#pragma unroll
        for (int i = 0; i < FR; ++i) {
            const int row = wr * 64 + half * 32 + i * 16 + m_;
#pragma unroll
            for (int kk = 0; kk < 2; ++kk)
                dst[i][kk] = *reinterpret_cast<const bf16x8*>(
                    &S[row * 64 + (((kk * 4 + kg) ^ (m_ & 7)) * 8)]);
        }
    };
    auto rdBp = [&](const uint16_t* S, int jp, bf16x8 (&dst)[2][2]) {
#pragma unroll
        for (int j = 0; j < 2; ++j) {
            const int row = wc * 64 + (jp * 2 + j) * 16 + m_;
#pragma unroll
            for (int kk = 0; kk < 2; ++kk)
                dst[j][kk] = *reinterpret_cast<const bf16x8*>(
                    &S[row * 64 + (((kk * 4 + kg) ^ (m_ & 7)) * 8)]);
        }
    };
    auto mfmaQ = [&](bf16x8 (&A4)[FR][2], bf16x8 (&B2)[2][2], int io, int jo) {
        __builtin_amdgcn_s_setprio(1);
#pragma unroll
        for (int i = 0; i < FR; ++i)
#pragma unroll
            for (int j = 0; j < 2; ++j) {
                acc[io + i][jo + j] = __builtin_amdgcn_mfma_f32_16x16x32_bf16(
                    A4[i][0], B2[j][0], acc[io + i][jo + j], 0, 0, 0);
                acc[io + i][jo + j] = __builtin_amdgcn_mfma_f32_16x16x32_bf16(
                    A4[i][1], B2[j][1], acc[io + i][jo + j], 0, 0, 0);
            }
        __builtin_amdgcn_s_setprio(0);
    };

    stageA(0, 0, 0); stageA(0, 0, 1); stageB(0, 0, 0); stageB(0, 0, 1);
    stageA(1, 64, 0); stageA(1, 64, 1);
    asm volatile("s_waitcnt vmcnt(4)" ::: "memory");
    BAR_();

    bf16x8 aLo[FR][2], aHi[FR][2], bLo[2][2], bHi[2][2];
    const int NT = K >> 6;   // 12
    for (int t = 0; t < NT; t += 2) {
        const bool last = (t + 2 >= NT);
        const int k1 = (t + 1) << 6, k2 = (t + 2) << 6, k3 = (t + 3) << 6;
        rdAh(As[0], 0, aLo); rdBp(Bs[0], 0, bLo);
        stageB(1, k1, 0);
        BAR_(); LGKM_(); mfmaQ(aLo, bLo, 0, 0); BAR_();
        rdAh(As[0], 1, aHi);
        stageB(1, k1, 1);
        BAR_(); LGKM_(); mfmaQ(aHi, bLo, FR, 0); BAR_();
        rdBp(Bs[0], 1, bHi);
        if (!last) stageA(0, k2, 0);
        BAR_(); LGKM_(); mfmaQ(aLo, bHi, 0, 2); BAR_();
        if (!last) { stageA(0, k2, 1);
                     asm volatile("s_waitcnt vmcnt(4)" ::: "memory"); }
        else       { asm volatile("s_waitcnt vmcnt(0)" ::: "memory"); }
        BAR_(); mfmaQ(aHi, bHi, FR, 2); BAR_();
        rdAh(As[1], 0, aLo); rdBp(Bs[1], 0, bLo);
        if (!last) stageB(0, k2, 0);
        BAR_(); LGKM_(); mfmaQ(aLo, bLo, 0, 0); BAR_();
        rdAh(As[1], 1, aHi);
        if (!last) stageB(0, k2, 1);
        BAR_(); LGKM_(); mfmaQ(aHi, bLo, FR, 0); BAR_();
        rdBp(Bs[1], 1, bHi);
        if (!last) stageA(1, k3, 0);
        BAR_(); LGKM_(); mfmaQ(aLo, bHi, 0, 2); BAR_();
        if (!last) { stageA(1, k3, 1);
                     asm volatile("s_waitcnt vmcnt(4)" ::: "memory"); }
        BAR_(); mfmaQ(aHi, bHi, FR, 2); BAR_();
    }

    // ---- stash V (bias applied, bf16) into dead As LDS ----
    // Layout: VL[c][128 s] with 16B-chunk swizzle chunk' = chunk ^ (c&7).
    uint16_t* VL = &As[0][0];
    __syncthreads();
#pragma unroll
    for (int i = 0; i < 4; ++i) {
#pragma unroll
        for (int j = 0; j < 4; ++j) {
            const int c  = wc * 64 + j * 16 + m_;
            const float bs = bias[n0 + c];
            const int sb = wr * 64 + i * 16 + kg * 4;     // s base (4 consec)
            const int ch = sb >> 3;
            const int off = (ch ^ (c & 7)) * 8 + (sb & 7);
            ushort4 o;
#pragma unroll
            for (int r = 0; r < 4; ++r)
                (&o.x)[r] = f2b(acc[i][j][r] + bs);
            *(ushort4*)(&VL[c * 128 + off]) = o;
        }
    }
    __syncthreads();

    if constexpr (T0) {
        // ---- stage 2 (t=0 only): 2 threads per column (s-halves), LDS combine.
        const int c  = tid & 127;                 // block-local col
        const int sh = tid >> 7;                  // s-half 0/1
        const int h  = hp * 2 + (c >> 6);
        const uint16_t* Am = MhT + (size_t)h * MSL_ * MSL_;  // row t=0
        float accd = 0.f;
#pragma unroll
        for (int sc0 = 0; sc0 < 8; ++sc0) {
            const int sc = sh * 8 + sc0;
            const uint16_t* vp = &VL[c * 128 + ((sc ^ (c & 7)) * 8)];
            const uint16_t* mp = &Am[sc * 8];
#pragma unroll
            for (int j = 0; j < 8; ++j)
                accd += b2f(vp[j]) * b2f(mp[j]);
        }
        if (sh) Pred[c] = accd;
        __syncthreads();
        if (!sh)
            out[(size_t)bb * D_ + n0 + c] = f2b(accd + Pred[c]);
    } else {
        // ---- stage 2: out[t][c] = sum_s MhT[h][t][s] * V[s][c] ----
        const int h = hp * 2 + wc;
        const uint16_t* Am = MhT + (size_t)h * MSL_ * MSL_;   // [t][s]
        f32x4 acc2[4][4] = {};
#pragma unroll
        for (int k0 = 0; k0 < 128; k0 += 32) {
            bf16x8 a2[4], b2[4];
#pragma unroll
            for (int i = 0; i < 4; ++i) {
                const int tr = wr * 64 + i * 16 + m_;
                a2[i] = *reinterpret_cast<const bf16x8*>(&Am[(size_t)tr * 128 + k0 + kg * 8]);
            }
#pragma unroll
            for (int j = 0; j < 4; ++j) {
                const int c  = wc * 64 + j * 16 + m_;
                const int ch = (k0 >> 3) + kg;
                b2[j] = *reinterpret_cast<const bf16x8*>(&VL[c * 128 + ((ch ^ (c & 7)) * 8)]);
            }
            __builtin_amdgcn_s_setprio(1);
#pragma unroll
            for (int i = 0; i < 4; ++i)
#pragma unroll
                for (int j = 0; j < 4; ++j)
                    acc2[i][j] = __builtin_amdgcn_mfma_f32_16x16x32_bf16(
                        a2[i], b2[j], acc2[i][j], 0, 0, 0);
            __builtin_amdgcn_s_setprio(0);
        }
#pragma unroll
        for (int i = 0; i < 4; ++i) {
#pragma unroll
            for (int j = 0; j < 4; ++j) {
                const int c = wc * 64 + j * 16 + m_;
#pragma unroll
                for (int r = 0; r < 4; ++r) {
                    const int tr = wr * 64 + i * 16 + kg * 4 + r;
                    out[(size_t)(bb * MSL_ + tr) * D_ + n0 + c] = f2b(acc2[i][j][r]);
                }
            }
        }
    }
}

// ---------------- M transpose: MhT[z][h][t][s] (bf16) = Mz[h][s][t] (f32) ----
__global__ __launch_bounds__(256)
void mtrans2(const float* __restrict__ M0, const float* __restrict__ M1,
             uint16_t* __restrict__ MT)
{
    __shared__ float tile[32][33];
    const int h  = blockIdx.x;
    const int ti = blockIdx.y & 3, si = blockIdx.y >> 2;
    const int z  = blockIdx.z;
    const int tx = threadIdx.x & 31, ty = threadIdx.x >> 5;  // 32x8
    const float* src = (z ? M1 : M0) + (size_t)h * MSL_ * MSL_;
    uint16_t*    dst = MT + (size_t)z * MT_SZ + (size_t)h * MSL_ * MSL_;
#pragma unroll
    for (int k = 0; k < 4; ++k)
        tile[ty + 8 * k][tx] = src[(size_t)(si * 32 + ty + 8 * k) * MSL_ + ti * 32 + tx];
    __syncthreads();
#pragma unroll
    for (int k = 0; k < 4; ++k)
        dst[(size_t)(ti * 32 + ty + 8 * k) * MSL_ + si * 32 + tx] = f2b(tile[tx][ty + 8 * k]);
}

// ---------------- Classifier (row stride parameterized) ----------------
__global__ void cls_kernel(const uint16_t* __restrict__ H, int rs,
                           const float* __restrict__ W,
                           const float* __restrict__ bias, float* __restrict__ out)
{
    const int b = blockIdx.x;
    const int lane = threadIdx.x;
    const uint16_t* row = H + (size_t)b * rs;
    float s0 = 0.f, s1 = 0.f;
    for (int d = lane; d < D_; d += 64) {
        const float xv = b2f(row[d]);
        s0 += xv * W[d];
        s1 += xv * W[D_ + d];
    }
#pragma unroll
    for (int off = 32; off > 0; off >>= 1) {
        s0 += __shfl_down(s0, off);
        s1 += __shfl_down(s1, off);
    }
    if (lane == 0) {
        out[b * 2 + 0] = s0 + bias[0];
        out[b * 2 + 1] = s1 + bias[1];
    }
}

extern "C" void kernel_launch(void* const* d_in, const int* in_sizes, int n_in,
                              void* d_out, int out_size, void* d_ws, size_t ws_size,
                              hipStream_t stream)
{
    const float* x     = (const float*)d_in[0];
    const float* M0    = (const float*)d_in[1];
    const float* M1    = (const float*)d_in[2];
    const float* Wv_w  = (const float*)d_in[3];
    const float* Wv_b  = (const float*)d_in[4];
    const float* d0_w  = (const float*)d_in[5];
    const float* d0_b  = (const float*)d_in[6];
    const float* lnw   = (const float*)d_in[7];
    const float* lnb   = (const float*)d_in[8];
    const float* ff0_w = (const float*)d_in[9];
    const float* ff0_b = (const float*)d_in[10];
    const float* ff1_w = (const float*)d_in[11];
    const float* ff1_b = (const float*)d_in[12];
    const float* lnffw = (const float*)d_in[13];
    const float* lnffb = (const float*)d_in[14];
    const float* Wv1_w = (const float*)d_in[15];
    const float* Wv1_b = (const float*)d_in[16];
    const float* d01_w = (const float*)d_in[17];
    const float* d01_b = (const float*)d_in[18];
    const float* lnw1  = (const float*)d_in[19];
    const float* lnb1  = (const float*)d_in[20];
    const float* ff01_w = (const float*)d_in[21];
    const float* ff01_b = (const float*)d_in[22];
    const float* ff11_w = (const float*)d_in[23];
    const float* ff11_b = (const float*)d_in[24];
    const float* lnffw1 = (const float*)d_in[25];
    const float* lnffb1 = (const float*)d_in[26];
    const float* cls_w  = (const float*)d_in[27];
    const float* cls_b  = (const float*)d_in[28];

    // ---- workspace layout (ushort elements) ----
    const size_t NB = (size_t)ROWS_ * D_;           // 12,582,912
    const size_t WTOT = 2ull * (2ull * D_ * D_ + 2ull * DI_ * D_);  // 11,796,480
    uint16_t* A0 = (uint16_t*)d_ws;
    uint16_t* A1 = A0 + NB;
    uint16_t* A2 = A1 + NB;
    uint16_t* wp = A2 + NB;
    uint16_t* bWv[2], *bD0[2], *bF0[2], *bF1[2];
    for (int blk = 0; blk < 2; ++blk) {
        bWv[blk] = wp; wp += (size_t)D_ * D_;
        bD0[blk] = wp; wp += (size_t)D_ * D_;
        bF0[blk] = wp; wp += (size_t)DI_ * D_;
        bF1[blk] = wp; wp += (size_t)D_ * DI_;
    }
    const size_t used_alias = (3ull * NB + WTOT) * sizeof(uint16_t);
    const size_t need_full  = used_alias + (4ull * NB + 2ull * MT_SZ) * sizeof(uint16_t);
    const bool full = (ws_size >= need_full);
    uint16_t* F  = full ? wp : A0;                  // FULL: dedicated; ALIAS: [A0;A1]
    uint16_t* mt = full ? (wp + 4ull * NB) : wp;    // MhT[2][12][128][128]
    const int CH = full ? ROWS_ : (ROWS_ / 2);      // 16384 or 8192

    // Block-2 tail buffers (128 rows), carved from A1 (dead in block 2).
    uint16_t* R0 = A1;                  // mix t=0 out (compact 128 x 768)
    uint16_t* R1 = A1 + 98304;          // dense0 out, 128 x 768
    uint16_t* RF = A1 + 2 * 98304;      // FFN-up out, 128 x 3072
    uint16_t* R2 = A1 + 2 * 98304 + 393216;  // FFN-down out, 128 x 768

    // ---- one batched convert launch for x + all 8 weight matrices ----
    CvtBatch cb;
    const float*  csrc[9] = {x, Wv_w, d0_w, ff0_w, ff1_w, Wv1_w, d01_w, ff01_w, ff11_w};
    uint16_t*     cdst[9] = {A2, bWv[0], bD0[0], bF0[0], bF1[0], bWv[1], bD0[1], bF0[1], bF1[1]};
    const size_t  cn[9]   = {NB, (size_t)D_*D_, (size_t)D_*D_, (size_t)DI_*D_, (size_t)D_*DI_,
                             (size_t)D_*D_, (size_t)D_*D_, (size_t)DI_*D_, (size_t)D_*DI_};
    int boff = 0;
    for (int s = 0; s < 9; ++s) {
        cb.src[s] = csrc[s]; cb.dst[s] = cdst[s];
        cb.n4[s]  = (int)(cn[s] / 4);
        cb.boff[s] = boff;
        boff += (cb.n4[s] + 255) / 256;
    }
    cb.boff[9] = boff;
    cvt_batch<<<dim3(boff), dim3(256), 0, stream>>>(cb);
    mtrans2<<<dim3(NH_, 16, 2), dim3(256), 0, stream>>>(M0, M1, mt);

    const dim3 blk256(256);

    // up (N=3072, full M): 128^2 (2 blk/CU schedule overlap) + CP supergroups
    // (B-resweep confined; avoids r12's 128MB FETCH).
    auto gemmUp = [&](const uint16_t* Ain, const uint16_t* Bw, const float* bias,
                      uint16_t* Cout, int M, int N, int K) {
        const int gx = N / 128;
        const dim3 grid(gx * (M / 128));
        gemm_bf16<2, 128, 1><<<grid, blk256, 0, stream>>>(
            Ain, Bw, bias, nullptr, nullptr, Cout, M, N, K, gx, K);
    };
    auto gemmSm = [&](int EPI, const uint16_t* Ain, const uint16_t* Bw,
                      const float* bias, const float* sc, const float* sh,
                      uint16_t* Cout, int M, int N, int K, int lda) {
        const int gx = N / 128;
        const dim3 grid(gx * (M / 128));
        if (EPI == 0)
            gemm_bf16<0, 128, 0><<<grid, blk256, 0, stream>>>(Ain, Bw, bias, sc, sh, Cout, M, N, K, gx, lda);
        else if (EPI == 1)
            gemm_bf16<1, 128, 0><<<grid, blk256, 0, stream>>>(Ain, Bw, bias, sc, sh, Cout, M, N, K, gx, lda);
        else
            gemm_bf16<2, 128, 0><<<grid, blk256, 0, stream>>>(Ain, Bw, bias, sc, sh, Cout, M, N, K, gx, lda);
    };

    // ---- Block 1: fused V+mix: A2 -> A1 ; dense0: A1 -> A2 ; FFN on A2. ----
    fused_vmix<0><<<dim3((D_ / 128) * BS_), blk256, 0, stream>>>(
        A2, bWv[0], Wv_b, mt, A1, D_ / 128);
    gemmSm(1, A1, bD0[0], d0_b, lnw, lnb, A2, ROWS_, D_, D_, D_);
    for (int c = 0; c < ROWS_; c += CH) {
        gemmUp(A2 + (size_t)c * D_, bF0[0], ff0_b, F, CH, DI_, D_);
        gemmSm(1, F, bF1[0], ff1_b, lnffw, lnffb, A2 + (size_t)c * D_, CH, D_, DI_, DI_);
    }

    // ---- Block 2: fused V+mix (t=0 only) -> R0 compact; tail on 128 rows. ----
    fused_vmix<1><<<dim3((D_ / 128) * BS_), blk256, 0, stream>>>(
        A2, bWv[1], Wv1_b, mt + MT_SZ, R0, D_ / 128);
    gemmSm(1, R0, bD0[1], d01_b, lnw1, lnb1, R1, 128, D_, D_, D_);
    gemmSm(2, R1, bF0[1], ff01_b, nullptr, nullptr, RF, 128, DI_, D_, D_);
    gemmSm(1, RF, bF1[1], ff11_b, lnffw1, lnffb1, R2, 128, D_, DI_, DI_);

    cls_kernel<<<dim3(BS_), dim3(64), 0, stream>>>(R2, D_, cls_w, cls_b, (float*)d_out);
}

// Round 21
// 332.410 us; speedup vs baseline: 1.0115x; 1.0115x over previous
//
#include <hip/hip_runtime.h>
#include <cstdint>
#include <cstddef>

#define BS_   128
#define MSL_  128
#define D_    768
#define NH_   12
#define DH_   64
#define DI_   3072
#define ROWS_ (BS_ * MSL_)   // 16384
#define MT_SZ (NH_ * MSL_ * MSL_)   // 196608 elements per M matrix

using bf16x8 = __attribute__((ext_vector_type(8))) __bf16;
using f32x4  = __attribute__((ext_vector_type(4))) float;

// Exact RNE f32 -> bf16 bits.
static __device__ __forceinline__ uint16_t f2b(float f) {
    uint32_t u = __builtin_bit_cast(uint32_t, f);
    u += 0x7fffu + ((u >> 16) & 1u);
    return (uint16_t)(u >> 16);
}
static __device__ __forceinline__ float b2f(uint16_t h) {
    uint32_t u = ((uint32_t)h) << 16;
    return __builtin_bit_cast(float, u);
}

// ---------------- batched f32 -> bf16 convert (one launch for all 9 jobs) ----
struct CvtBatch {
    const float* src[9];
    uint16_t*    dst[9];
    int          n4[9];
    int          boff[10];   // prefix block offsets
};
__global__ __launch_bounds__(256)
void cvt_batch(CvtBatch cb) {
    const int g = blockIdx.x;
    int seg = 0;
    while (seg < 8 && g >= cb.boff[seg + 1]) ++seg;
    const int i = (g - cb.boff[seg]) * 256 + threadIdx.x;
    if (i < cb.n4[seg]) {
        float4 v = ((const float4*)cb.src[seg])[i];
        ushort4 o;
        o.x = f2b(v.x); o.y = f2b(v.y); o.z = f2b(v.z); o.w = f2b(v.w);
        ((ushort4*)cb.dst[seg])[i] = o;
    }
}

// async global->LDS, 16B per lane. LDS dest is wave-uniform base (+lane*16 in HW).
static __device__ __forceinline__ void gload16(const uint16_t* g, uint16_t* l) {
    __builtin_amdgcn_global_load_lds(
        (__attribute__((address_space(1))) void*)(uintptr_t)g,
        (__attribute__((address_space(3))) void*)(uintptr_t)l,
        16, 0, 0);
}

#define BAR_()  __builtin_amdgcn_s_barrier()
#define LGKM_() asm volatile("s_waitcnt lgkmcnt(0)" ::: "memory")

// ---------------- bf16 MFMA GEMM: C = epi(A @ B^T + bias) ----------------
// A: [M][K] bf16 rows at stride lda, B: [N][K] bf16 row-major, C: [M][N] bf16.
// EPI: 0 = +bias; 1 = (+bias)*scale+shift; 2 = relu(+bias)
// BM: 256 (512 thr, 8 waves, 128KB LDS) or 128 (256 thr, 4 waves, 64KB LDS
//     -> 2 blk/CU; best for N=768 long-K shapes, r11).
// CP (column-pair supergroups, up-GEMM 256^2): within each XCD chunk
//   (ry rows x gx cols), iterate 2-col x ry-row supergroups -> B-resweep
//   confined; FETCH 72->57MB measured (r19). r20 A/B: 128^2+CP loses to
//   256^2+CP (91.6MB FETCH, same 37% MfmaUtil) — NT=12 schedule is the
//   binding constraint, not occupancy/traffic.
// 8-phase counted-vmcnt schedule (r9-proven, de-pinned; no sched_barrier).
// LDS chunk swizzle: phys16Bchunk = logical ^ (row&7), BOTH sides (rule #21).
// XCD swizzle bijective when nwg%8==0; identity fallback otherwise.
template<int EPI, int BM, int CP>
__global__ __launch_bounds__(BM * 2, 2)
void gemm_bf16(const uint16_t* __restrict__ A, const uint16_t* __restrict__ B,
               const float* __restrict__ bias, const float* __restrict__ scale,
               const float* __restrict__ shift, uint16_t* __restrict__ C,
               int M, int N, int K, int gx, int lda)
{
    constexpr int NTHR = BM * 2;
    constexpr int FR   = BM / 64;
    __shared__ __align__(16) uint16_t As[2][BM * 64];
    __shared__ __align__(16) uint16_t Bs[2][BM * 64];
    const int tid  = threadIdx.x;
    const int lane = tid & 63;
    const int m_   = lane & 15;
    const int kg   = lane >> 4;
    const int w    = tid >> 6;
    const int wr   = w / FR;
    const int wc   = w % FR;

    const int nwg = gridDim.x;
    const int q   = nwg >> 3;
    int m0, n0;
    if constexpr (CP) {
        const int x   = blockIdx.x & 7;
        const int lid = blockIdx.x >> 3;       // [0, q)
        const int ry  = q / gx;                // rows per XCD chunk
        const int g2  = 2 * ry;
        const int sg  = lid / g2;              // supergroup (2 cols x ry rows)
        const int r   = lid % g2;
        m0 = (x * ry + (r >> 1)) * BM;
        n0 = (sg * 2 + (r & 1)) * BM;
    } else {
        const int wg = ((nwg & 7) == 0) ? ((blockIdx.x & 7) * q + (blockIdx.x >> 3))
                                        : (int)blockIdx.x;
        m0 = (wg / gx) * BM;
        n0 = (wg % gx) * BM;
    }

    f32x4 acc[2 * FR][4] = {};

    int srow[4], ssl[4], sbase[4];
#pragma unroll
    for (int it = 0; it < 4; ++it) {
        const int c = it * NTHR + tid;
        srow[it]  = c >> 3;
        ssl[it]   = (c & 7) ^ (srow[it] & 7);
        sbase[it] = (it * NTHR + (tid & (NTHR - 64))) * 8;
    }
    auto stageA = [&](int buf, int k0, int half) {
        const int it0 = half * 2, it1 = it0 + 1;
        gload16(A + (size_t)(m0 + srow[it0]) * lda + k0 + ssl[it0] * 8, &As[buf][sbase[it0]]);
        gload16(A + (size_t)(m0 + srow[it1]) * lda + k0 + ssl[it1] * 8, &As[buf][sbase[it1]]);
    };
    auto stageB = [&](int buf, int k0, int half) {
        const int it0 = half * 2, it1 = it0 + 1;
        gload16(B + (size_t)(n0 + srow[it0]) * K + k0 + ssl[it0] * 8, &Bs[buf][sbase[it0]]);
        gload16(B + (size_t)(n0 + srow[it1]) * K + k0 + ssl[it1] * 8, &Bs[buf][sbase[it1]]);
    };

    auto rdAh = [&](const uint16_t* S, int half, bf16x8 (&dst)[FR][2]) {
#pragma unroll
        for (int i = 0; i < FR; ++i) {
            const int row = wr * (BM / 2) + half * (FR * 16) + i * 16 + m_;
#pragma unroll
            for (int kk = 0; kk < 2; ++kk)
                dst[i][kk] = *reinterpret_cast<const bf16x8*>(
                    &S[row * 64 + (((kk * 4 + kg) ^ (m_ & 7)) * 8)]);
        }
    };
    auto rdBp = [&](const uint16_t* S, int jp, bf16x8 (&dst)[2][2]) {
#pragma unroll
        for (int j = 0; j < 2; ++j) {
            const int row = wc * 64 + (jp * 2 + j) * 16 + m_;
#pragma unroll
            for (int kk = 0; kk < 2; ++kk)
                dst[j][kk] = *reinterpret_cast<const bf16x8*>(
                    &S[row * 64 + (((kk * 4 + kg) ^ (m_ & 7)) * 8)]);
        }
    };
    auto mfmaQ = [&](bf16x8 (&A4)[FR][2], bf16x8 (&B2)[2][2], int io, int jo) {
        __builtin_amdgcn_s_setprio(1);
#pragma unroll
        for (int i = 0; i < FR; ++i)
#pragma unroll
            for (int j = 0; j < 2; ++j) {
                acc[io + i][jo + j] = __builtin_amdgcn_mfma_f32_16x16x32_bf16(
                    A4[i][0], B2[j][0], acc[io + i][jo + j], 0, 0, 0);
                acc[io + i][jo + j] = __builtin_amdgcn_mfma_f32_16x16x32_bf16(
                    A4[i][1], B2[j][1], acc[io + i][jo + j], 0, 0, 0);
            }
        __builtin_amdgcn_s_setprio(0);
    };

    stageA(0, 0, 0); stageA(0, 0, 1); stageB(0, 0, 0); stageB(0, 0, 1);
    stageA(1, 64, 0); stageA(1, 64, 1);
    asm volatile("s_waitcnt vmcnt(4)" ::: "memory");
    BAR_();

    bf16x8 aLo[FR][2], aHi[FR][2], bLo[2][2], bHi[2][2];
    const int NT = K >> 6;
    for (int t = 0; t < NT; t += 2) {
        const bool last = (t + 2 >= NT);
        const int k1 = (t + 1) << 6, k2 = (t + 2) << 6, k3 = (t + 3) << 6;

        rdAh(As[0], 0, aLo); rdBp(Bs[0], 0, bLo);
        stageB(1, k1, 0);
        BAR_(); LGKM_(); mfmaQ(aLo, bLo, 0, 0); BAR_();
        rdAh(As[0], 1, aHi);
        stageB(1, k1, 1);
        BAR_(); LGKM_(); mfmaQ(aHi, bLo, FR, 0); BAR_();
        rdBp(Bs[0], 1, bHi);
        if (!last) stageA(0, k2, 0);
        BAR_(); LGKM_(); mfmaQ(aLo, bHi, 0, 2); BAR_();
        if (!last) { stageA(0, k2, 1);
                     asm volatile("s_waitcnt vmcnt(4)" ::: "memory"); }
        else       { asm volatile("s_waitcnt vmcnt(0)" ::: "memory"); }
        BAR_(); mfmaQ(aHi, bHi, FR, 2); BAR_();

        rdAh(As[1], 0, aLo); rdBp(Bs[1], 0, bLo);
        if (!last) stageB(0, k2, 0);
        BAR_(); LGKM_(); mfmaQ(aLo, bLo, 0, 0); BAR_();
        rdAh(As[1], 1, aHi);
        if (!last) stageB(0, k2, 1);
        BAR_(); LGKM_(); mfmaQ(aHi, bLo, FR, 0); BAR_();
        rdBp(Bs[1], 1, bHi);
        if (!last) stageA(1, k3, 0);
        BAR_(); LGKM_(); mfmaQ(aLo, bHi, 0, 2); BAR_();
        if (!last) { stageA(1, k3, 1);
                     asm volatile("s_waitcnt vmcnt(4)" ::: "memory"); }
        BAR_(); mfmaQ(aHi, bHi, FR, 2); BAR_();
    }

    const int r0 = m0 + wr * (BM / 2);
    const int c0 = n0 + wc * 64;
#pragma unroll
    for (int i = 0; i < 2 * FR; ++i) {
#pragma unroll
        for (int j = 0; j < 4; ++j) {
            const int col = c0 + j * 16 + m_;
            const float bs = bias[col];
#pragma unroll
            for (int r = 0; r < 4; ++r) {
                float v = acc[i][j][r] + bs;
                if constexpr (EPI == 1) v = v * scale[col] + shift[col];
                if constexpr (EPI == 2) v = fmaxf(v, 0.f);
                const int rowo = r0 + i * 16 + kg * 4 + r;
                C[(size_t)rowo * N + col] = f2b(v);
            }
        }
    }
}

// ---------- Fused V-GEMM + head mixing (BM=128, one batch per M-tile) -------
// Stage 1: V-tile[s=0..127][128 hd-cols] = hin[b] @ Wv^T + b  (8-phase loop).
// Stash V (bf16) into dead As LDS using the proven chunk-XOR layout.
// Stage 2 (T0=0): out[b,t,hd] = sum_s MhT[h][t][s] * V[s][hd]  (K=128 MFMA).
// Stage 2 (T0=1, block 2): only t=0 survives — all 256 threads: each column
// handled by 2 threads (s-halves), partials combined via LDS.
template<int T0>
__global__ __launch_bounds__(256, 2)
void fused_vmix(const uint16_t* __restrict__ A, const uint16_t* __restrict__ B,
                const float* __restrict__ bias, const uint16_t* __restrict__ MhT,
                uint16_t* __restrict__ out, int gx)
{
    constexpr int BM = 128, NTHR = 256, FR = 2;
    const int K = D_;
    __shared__ __align__(16) uint16_t As[2][BM * 64];
    __shared__ __align__(16) uint16_t Bs[2][BM * 64];
    __shared__ float Pred[128];
    const int tid  = threadIdx.x;
    const int lane = tid & 63;
    const int m_   = lane & 15;
    const int kg   = lane >> 4;
    const int w    = tid >> 6;
    const int wr   = w / FR;   // 0..1 (s-half / t-half)
    const int wc   = w % FR;   // 0..1 (hd-half; also head within pair)

    const int nwg = gridDim.x;        // 768 (%8==0)
    const int q   = nwg >> 3;
    const int wg  = (blockIdx.x & 7) * q + (blockIdx.x >> 3);
    const int bb  = wg / gx;          // batch
    const int hp  = wg % gx;          // head pair
    const int m0  = bb * BM;          // rows of A (= b*128 + s)
    const int n0  = hp * BM;          // hd column base

    f32x4 acc[4][4] = {};

    int srow[4], ssl[4], sbase[4];
#pragma unroll
    for (int it = 0; it < 4; ++it) {
        const int c = it * NTHR + tid;
        srow[it]  = c >> 3;
        ssl[it]   = (c & 7) ^ (srow[it] & 7);
        sbase[it] = (it * NTHR + (tid & (NTHR - 64))) * 8;
    }
    auto stageA = [&](int buf, int k0, int half) {
        const int it0 = half * 2, it1 = it0 + 1;
        gload16(A + (size_t)(m0 + srow[it0]) * K + k0 + ssl[it0] * 8, &As[buf][sbase[it0]]);
        gload16(A + (size_t)(m0 + srow[it1]) * K + k0 + ssl[it1] * 8, &As[buf][sbase[it1]]);
    };
    auto stageB = [&](int buf, int k0, int half) {
        const int it0 = half * 2, it1 = it0 + 1;
        gload16(B + (size_t)(n0 + srow[it0]) * K + k0 + ssl[it0] * 8, &Bs[buf][sbase[it0]]);
        gload16(B + (size_t)(n0 + srow[it1]) * K + k0 + ssl[it1] * 8, &Bs[buf][sbase[it1]]);
    };
    auto rdAh = [&](const uint16_t* S, int half, bf16x8 (&dst)[FR][2]) {
#pragma unroll
        for (int i = 0; i < FR; ++i) {
            const int row = wr * 64 + half * 32 + i * 16 + m_;
#pragma unroll
            for (int kk = 0; kk < 2; ++kk)
                dst[i][kk] = *reinterpret_cast<const bf16x8*>(
                    &S[row * 64 + (((kk * 4 + kg) ^ (m_ & 7)) * 8)]);
        }
    };
    auto rdBp = [&](const uint16_t* S, int jp, bf16x8 (&dst)[2][2]) {
#pragma unroll
        for (int j = 0; j < 2; ++j) {
            const int row = wc * 64 + (jp * 2 + j) * 16 + m_;
#pragma unroll
            for (int kk = 0; kk < 2; ++kk)
                dst[j][kk] = *reinterpret_cast<const bf16x8*>(
                    &S[row * 64 + (((kk * 4 + kg) ^ (m_ & 7)) * 8)]);
        }
    };
    auto mfmaQ = [&](bf16x8 (&A4)[FR][2], bf16x8 (&B2)[2][2], int io, int jo) {
        __builtin_amdgcn_s_setprio(1);
#pragma unroll
        for (int i = 0; i < FR; ++i)
#pragma unroll
            for (int j = 0; j < 2; ++j) {
                acc[io + i][jo + j] = __builtin_amdgcn_mfma_f32_16x16x32_bf16(
                    A4[i][0], B2[j][0], acc[io + i][jo + j], 0, 0, 0);
                acc[io + i][jo + j] = __builtin_amdgcn_mfma_f32_16x16x32_bf16(
                    A4[i][1], B2[j][1], acc[io + i][jo + j], 0, 0, 0);
            }
        __builtin_amdgcn_s_setprio(0);
    };

    stageA(0, 0, 0); stageA(0, 0, 1); stageB(0, 0, 0); stageB(0, 0, 1);
    stageA(1, 64, 0); stageA(1, 64, 1);
    asm volatile("s_waitcnt vmcnt(4)" ::: "memory");
    BAR_();

    bf16x8 aLo[FR][2], aHi[FR][2], bLo[2][2], bHi[2][2];
    const int NT = K >> 6;   // 12
    for (int t = 0; t < NT; t += 2) {
        const bool last = (t + 2 >= NT);
        const int k1 = (t + 1) << 6, k2 = (t + 2) << 6, k3 = (t + 3) << 6;
        rdAh(As[0], 0, aLo); rdBp(Bs[0], 0, bLo);
        stageB(1, k1, 0);
        BAR_(); LGKM_(); mfmaQ(aLo, bLo, 0, 0); BAR_();
        rdAh(As[0], 1, aHi);
        stageB(1, k1, 1);
        BAR_(); LGKM_(); mfmaQ(aHi, bLo, FR, 0); BAR_();
        rdBp(Bs[0], 1, bHi);
        if (!last) stageA(0, k2, 0);
        BAR_(); LGKM_(); mfmaQ(aLo, bHi, 0, 2); BAR_();
        if (!last) { stageA(0, k2, 1);
                     asm volatile("s_waitcnt vmcnt(4)" ::: "memory"); }
        else       { asm volatile("s_waitcnt vmcnt(0)" ::: "memory"); }
        BAR_(); mfmaQ(aHi, bHi, FR, 2); BAR_();
        rdAh(As[1], 0, aLo); rdBp(Bs[1], 0, bLo);
        if (!last) stageB(0, k2, 0);
        BAR_(); LGKM_(); mfmaQ(aLo, bLo, 0, 0); BAR_();
        rdAh(As[1], 1, aHi);
        if (!last) stageB(0, k2, 1);
        BAR_(); LGKM_(); mfmaQ(aHi, bLo, FR, 0); BAR_();
        rdBp(Bs[1], 1, bHi);
        if (!last) stageA(1, k3, 0);
        BAR_(); LGKM_(); mfmaQ(aLo, bHi, 0, 2); BAR_();
        if (!last) { stageA(1, k3, 1);
                     asm volatile("s_waitcnt vmcnt(4)" ::: "memory"); }
        BAR_(); mfmaQ(aHi, bHi, FR, 2); BAR_();
    }

    // ---- stash V (bias applied, bf16) into dead As LDS ----
    // Layout: VL[c][128 s] with 16B-chunk swizzle chunk' = chunk ^ (c&7).
    uint16_t* VL = &As[0][0];
    __syncthreads();
#pragma unroll
    for (int i = 0; i < 4; ++i) {
#pragma unroll
        for (int j = 0; j < 4; ++j) {
            const int c  = wc * 64 + j * 16 + m_;
            const float bs = bias[n0 + c];
            const int sb = wr * 64 + i * 16 + kg * 4;     // s base (4 consec)
            const int ch = sb >> 3;
            const int off = (ch ^ (c & 7)) * 8 + (sb & 7);
            ushort4 o;
#pragma unroll
            for (int r = 0; r < 4; ++r)
                (&o.x)[r] = f2b(acc[i][j][r] + bs);
            *(ushort4*)(&VL[c * 128 + off]) = o;
        }
    }
    __syncthreads();

    if constexpr (T0) {
        // ---- stage 2 (t=0 only): 2 threads per column (s-halves), LDS combine.
        const int c  = tid & 127;                 // block-local col
        const int sh = tid >> 7;                  // s-half 0/1
        const int h  = hp * 2 + (c >> 6);
        const uint16_t* Am = MhT + (size_t)h * MSL_ * MSL_;  // row t=0
        float accd = 0.f;
#pragma unroll
        for (int sc0 = 0; sc0 < 8; ++sc0) {
            const int sc = sh * 8 + sc0;
            const uint16_t* vp = &VL[c * 128 + ((sc ^ (c & 7)) * 8)];
            const uint16_t* mp = &Am[sc * 8];
#pragma unroll
            for (int j = 0; j < 8; ++j)
                accd += b2f(vp[j]) * b2f(mp[j]);
        }
        if (sh) Pred[c] = accd;
        __syncthreads();
        if (!sh)
            out[(size_t)bb * D_ + n0 + c] = f2b(accd + Pred[c]);
    } else {
        // ---- stage 2: out[t][c] = sum_s MhT[h][t][s] * V[s][c] ----
        const int h = hp * 2 + wc;
        const uint16_t* Am = MhT + (size_t)h * MSL_ * MSL_;   // [t][s]
        f32x4 acc2[4][4] = {};
#pragma unroll
        for (int k0 = 0; k0 < 128; k0 += 32) {
            bf16x8 a2[4], b2[4];
#pragma unroll
            for (int i = 0; i < 4; ++i) {
                const int tr = wr * 64 + i * 16 + m_;
                a2[i] = *reinterpret_cast<const bf16x8*>(&Am[(size_t)tr * 128 + k0 + kg * 8]);
            }
#pragma unroll
            for (int j = 0; j < 4; ++j) {
                const int c  = wc * 64 + j * 16 + m_;
                const int ch = (k0 >> 3) + kg;
                b2[j] = *reinterpret_cast<const bf16x8*>(&VL[c * 128 + ((ch ^ (c & 7)) * 8)]);
            }
            __builtin_amdgcn_s_setprio(1);
#pragma unroll
            for (int i = 0; i < 4; ++i)
#pragma unroll
                for (int j = 0; j < 4; ++j)
                    acc2[i][j] = __builtin_amdgcn_mfma_f32_16x16x32_bf16(
                        a2[i], b2[j], acc2[i][j], 0, 0, 0);
            __builtin_amdgcn_s_setprio(0);
        }
#pragma unroll
        for (int i = 0; i < 4; ++i) {
#pragma unroll
            for (int j = 0; j < 4; ++j) {
                const int c = wc * 64 + j * 16 + m_;
#pragma unroll
                for (int r = 0; r < 4; ++r) {
                    const int tr = wr * 64 + i * 16 + kg * 4 + r;
                    out[(size_t)(bb * MSL_ + tr) * D_ + n0 + c] = f2b(acc2[i][j][r]);
                }
            }
        }
    }
}

// ---------------- M transpose: MhT[z][h][t][s] (bf16) = Mz[h][s][t] (f32) ----
__global__ __launch_bounds__(256)
void mtrans2(const float* __restrict__ M0, const float* __restrict__ M1,
             uint16_t* __restrict__ MT)
{
    __shared__ float tile[32][33];
    const int h  = blockIdx.x;
    const int ti = blockIdx.y & 3, si = blockIdx.y >> 2;
    const int z  = blockIdx.z;
    const int tx = threadIdx.x & 31, ty = threadIdx.x >> 5;  // 32x8
    const float* src = (z ? M1 : M0) + (size_t)h * MSL_ * MSL_;
    uint16_t*    dst = MT + (size_t)z * MT_SZ + (size_t)h * MSL_ * MSL_;
#pragma unroll
    for (int k = 0; k < 4; ++k)
        tile[ty + 8 * k][tx] = src[(size_t)(si * 32 + ty + 8 * k) * MSL_ + ti * 32 + tx];
    __syncthreads();
#pragma unroll
    for (int k = 0; k < 4; ++k)
        dst[(size_t)(ti * 32 + ty + 8 * k) * MSL_ + si * 32 + tx] = f2b(tile[tx][ty + 8 * k]);
}

// ---------------- Classifier (row stride parameterized) ----------------
__global__ void cls_kernel(const uint16_t* __restrict__ H, int rs,
                           const float* __restrict__ W,
                           const float* __restrict__ bias, float* __restrict__ out)
{
    const int b = blockIdx.x;
    const int lane = threadIdx.x;
    const uint16_t* row = H + (size_t)b * rs;
    float s0 = 0.f, s1 = 0.f;
    for (int d = lane; d < D_; d += 64) {
        const float xv = b2f(row[d]);
        s0 += xv * W[d];
        s1 += xv * W[D_ + d];
    }
#pragma unroll
    for (int off = 32; off > 0; off >>= 1) {
        s0 += __shfl_down(s0, off);
        s1 += __shfl_down(s1, off);
    }
    if (lane == 0) {
        out[b * 2 + 0] = s0 + bias[0];
        out[b * 2 + 1] = s1 + bias[1];
    }
}

extern "C" void kernel_launch(void* const* d_in, const int* in_sizes, int n_in,
                              void* d_out, int out_size, void* d_ws, size_t ws_size,
                              hipStream_t stream)
{
    const float* x     = (const float*)d_in[0];
    const float* M0    = (const float*)d_in[1];
    const float* M1    = (const float*)d_in[2];
    const float* Wv_w  = (const float*)d_in[3];
    const float* Wv_b  = (const float*)d_in[4];
    const float* d0_w  = (const float*)d_in[5];
    const float* d0_b  = (const float*)d_in[6];
    const float* lnw   = (const float*)d_in[7];
    const float* lnb   = (const float*)d_in[8];
    const float* ff0_w = (const float*)d_in[9];
    const float* ff0_b = (const float*)d_in[10];
    const float* ff1_w = (const float*)d_in[11];
    const float* ff1_b = (const float*)d_in[12];
    const float* lnffw = (const float*)d_in[13];
    const float* lnffb = (const float*)d_in[14];
    const float* Wv1_w = (const float*)d_in[15];
    const float* Wv1_b = (const float*)d_in[16];
    const float* d01_w = (const float*)d_in[17];
    const float* d01_b = (const float*)d_in[18];
    const float* lnw1  = (const float*)d_in[19];
    const float* lnb1  = (const float*)d_in[20];
    const float* ff01_w = (const float*)d_in[21];
    const float* ff01_b = (const float*)d_in[22];
    const float* ff11_w = (const float*)d_in[23];
    const float* ff11_b = (const float*)d_in[24];
    const float* lnffw1 = (const float*)d_in[25];
    const float* lnffb1 = (const float*)d_in[26];
    const float* cls_w  = (const float*)d_in[27];
    const float* cls_b  = (const float*)d_in[28];

    // ---- workspace layout (ushort elements) ----
    const size_t NB = (size_t)ROWS_ * D_;           // 12,582,912
    const size_t WTOT = 2ull * (2ull * D_ * D_ + 2ull * DI_ * D_);  // 11,796,480
    uint16_t* A0 = (uint16_t*)d_ws;
    uint16_t* A1 = A0 + NB;
    uint16_t* A2 = A1 + NB;
    uint16_t* wp = A2 + NB;
    uint16_t* bWv[2], *bD0[2], *bF0[2], *bF1[2];
    for (int blk = 0; blk < 2; ++blk) {
        bWv[blk] = wp; wp += (size_t)D_ * D_;
        bD0[blk] = wp; wp += (size_t)D_ * D_;
        bF0[blk] = wp; wp += (size_t)DI_ * D_;
        bF1[blk] = wp; wp += (size_t)D_ * DI_;
    }
    const size_t used_alias = (3ull * NB + WTOT) * sizeof(uint16_t);
    const size_t need_full  = used_alias + (4ull * NB + 2ull * MT_SZ) * sizeof(uint16_t);
    const bool full = (ws_size >= need_full);
    uint16_t* F  = full ? wp : A0;                  // FULL: dedicated; ALIAS: [A0;A1]
    uint16_t* mt = full ? (wp + 4ull * NB) : wp;    // MhT[2][12][128][128]
    const int CH = full ? ROWS_ : (ROWS_ / 2);      // 16384 or 8192

    // Block-2 tail buffers (128 rows), carved from A1 (dead in block 2).
    uint16_t* R0 = A1;                  // mix t=0 out (compact 128 x 768)
    uint16_t* R1 = A1 + 98304;          // dense0 out, 128 x 768
    uint16_t* RF = A1 + 2 * 98304;      // FFN-up out, 128 x 3072
    uint16_t* R2 = A1 + 2 * 98304 + 393216;  // FFN-down out, 128 x 768

    // ---- one batched convert launch for x + all 8 weight matrices ----
    CvtBatch cb;
    const float*  csrc[9] = {x, Wv_w, d0_w, ff0_w, ff1_w, Wv1_w, d01_w, ff01_w, ff11_w};
    uint16_t*     cdst[9] = {A2, bWv[0], bD0[0], bF0[0], bF1[0], bWv[1], bD0[1], bF0[1], bF1[1]};
    const size_t  cn[9]   = {NB, (size_t)D_*D_, (size_t)D_*D_, (size_t)DI_*D_, (size_t)D_*DI_,
                             (size_t)D_*D_, (size_t)D_*D_, (size_t)DI_*D_, (size_t)D_*DI_};
    int boff = 0;
    for (int s = 0; s < 9; ++s) {
        cb.src[s] = csrc[s]; cb.dst[s] = cdst[s];
        cb.n4[s]  = (int)(cn[s] / 4);
        cb.boff[s] = boff;
        boff += (cb.n4[s] + 255) / 256;
    }
    cb.boff[9] = boff;
    cvt_batch<<<dim3(boff), dim3(256), 0, stream>>>(cb);
    mtrans2<<<dim3(NH_, 16, 2), dim3(256), 0, stream>>>(M0, M1, mt);

    const dim3 blk256(256);
    const dim3 blk512(512);

    // up (N=3072, full M): 256^2 + CP supergroups (r19 best: 87.7us, 57MB).
    auto gemmUp = [&](const uint16_t* Ain, const uint16_t* Bw, const float* bias,
                      uint16_t* Cout, int M, int N, int K) {
        const int gx = N / 256;
        const dim3 grid(gx * (M / 256));
        gemm_bf16<2, 256, 1><<<grid, blk512, 0, stream>>>(
            Ain, Bw, bias, nullptr, nullptr, Cout, M, N, K, gx, K);
    };
    auto gemmSm = [&](int EPI, const uint16_t* Ain, const uint16_t* Bw,
                      const float* bias, const float* sc, const float* sh,
                      uint16_t* Cout, int M, int N, int K, int lda) {
        const int gx = N / 128;
        const dim3 grid(gx * (M / 128));
        if (EPI == 0)
            gemm_bf16<0, 128, 0><<<grid, blk256, 0, stream>>>(Ain, Bw, bias, sc, sh, Cout, M, N, K, gx, lda);
        else if (EPI == 1)
            gemm_bf16<1, 128, 0><<<grid, blk256, 0, stream>>>(Ain, Bw, bias, sc, sh, Cout, M, N, K, gx, lda);
        else
            gemm_bf16<2, 128, 0><<<grid, blk256, 0, stream>>>(Ain, Bw, bias, sc, sh, Cout, M, N, K, gx, lda);
    };

    // ---- Block 1: fused V+mix: A2 -> A1 ; dense0: A1 -> A2 ; FFN on A2. ----
    fused_vmix<0><<<dim3((D_ / 128) * BS_), blk256, 0, stream>>>(
        A2, bWv[0], Wv_b, mt, A1, D_ / 128);
    gemmSm(1, A1, bD0[0], d0_b, lnw, lnb, A2, ROWS_, D_, D_, D_);
    for (int c = 0; c < ROWS_; c += CH) {
        gemmUp(A2 + (size_t)c * D_, bF0[0], ff0_b, F, CH, DI_, D_);
        gemmSm(1, F, bF1[0], ff1_b, lnffw, lnffb, A2 + (size_t)c * D_, CH, D_, DI_, DI_);
    }

    // ---- Block 2: fused V+mix (t=0 only) -> R0 compact; tail on 128 rows. ----
    fused_vmix<1><<<dim3((D_ / 128) * BS_), blk256, 0, stream>>>(
        A2, bWv[1], Wv1_b, mt + MT_SZ, R0, D_ / 128);
    gemmSm(1, R0, bD0[1], d01_b, lnw1, lnb1, R1, 128, D_, D_, D_);
    gemmSm(2, R1, bF0[1], ff01_b, nullptr, nullptr, RF, 128, DI_, D_, D_);
    gemmSm(1, RF, bF1[1], ff11_b, lnffw1, lnffb1, R2, 128, D_, DI_, DI_);

    cls_kernel<<<dim3(BS_), dim3(64), 0, stream>>>(R2, D_, cls_w, cls_b, (float*)d_out);
}